// Round 9
// baseline (424.193 us; speedup 1.0000x reference)
//
#include <hip/hip_runtime.h>
#include <math.h>

#define HIDDEN 256
#define NUM_CLASSES 53
#define NWAVES 4
#define BLOCK (NWAVES * 64)
#define KP 4                       // rows per wave-slot per iteration
#define SPLIT 4                    // blocks per bag (phase 1)
#define PART_STRIDE 520            // floats per partial record (512 o + 2 l + pad)
#define COMB_FLOATS (NUM_CLASSES * 2 * HIDDEN)
#define COMB_BYTES (COMB_FLOATS * 4)

// v += dpp_mov(v, CTRL); bound_ctrl: out-of-range sources read 0
template <int CTRL>
__device__ __forceinline__ float dpp_add(float v) {
    int t = __builtin_amdgcn_update_dpp(0, __float_as_int(v), CTRL, 0xf, 0xf, true);
    return v + __int_as_float(t);
}

// Full 64-lane sum -> wave-uniform (readlane 63)
__device__ __forceinline__ float wave_sum64(float v) {
    v = dpp_add<0x111>(v);   // row_shr:1
    v = dpp_add<0x112>(v);   // row_shr:2
    v = dpp_add<0x114>(v);   // row_shr:4
    v = dpp_add<0x118>(v);   // row_shr:8
    v = dpp_add<0x142>(v);   // row_bcast:15
    v = dpp_add<0x143>(v);   // row_bcast:31 -> lane63 = total
    return __int_as_float(__builtin_amdgcn_readlane(__float_as_int(v), 63));
}

// Setup: comb[c][0:256] = rel_emb0[rl[c].x], comb[c][256:512] = rel_emb1[rl[c].y]
__global__ void build_comb_kernel(const float* __restrict__ rel_emb0,
                                  const float* __restrict__ rel_emb1,
                                  const int* __restrict__ relation_levels,
                                  float* __restrict__ comb) {
    const int c = blockIdx.x;
    const int t = threadIdx.x;
    const int2 rl = *reinterpret_cast<const int2*>(relation_levels + 2 * c);
    comb[c * 512 + t]       = rel_emb0[rl.x * HIDDEN + t];
    comb[c * 512 + 256 + t] = rel_emb1[rl.y * HIDDEN + t];
}

// ---- Phase 1: each block = (bag, j) computes a partial (o0,o1,l0,l1) ----
__global__ __launch_bounds__(BLOCK, 8) void hattn_partial_kernel(
    const float* __restrict__ x,
    const float* __restrict__ comb,
    const int* __restrict__ label_index,
    const int* __restrict__ scope,
    float* __restrict__ part)
{
    const int blk = blockIdx.x;
    const int bag = blk >> 2;          // / SPLIT
    const int j   = blk & (SPLIT - 1);
    const int start = __builtin_amdgcn_readfirstlane(scope[bag]);
    const int end   = __builtin_amdgcn_readfirstlane(scope[bag + 1]);

    const int tid  = threadIdx.x;
    const int lane = tid & 63;
    const int wave = tid >> 6;                 // 0..3
    const int col  = lane << 2;                // 4 hidden cols per lane
    const int slot = j * NWAVES + wave;        // 0..15

    float4 o0 = make_float4(0,0,0,0), o1 = make_float4(0,0,0,0);
    float  l0 = 0.f, l1 = 0.f;

    for (int rb0 = start + slot * KP; rb0 < end; rb0 += SPLIT * NWAVES * KP) {
        const int rb = __builtin_amdgcn_readfirstlane(rb0);
        const int nv = end - rb;

        int    lbl[KP];
        float4 xv[KP];
        #pragma unroll
        for (int k = 0; k < KP; ++k) {
            const int rc = rb + ((k < nv) ? k : 0);
            lbl[k] = label_index[rc];                              // uniform -> s_load
            xv[k]  = *reinterpret_cast<const float4*>(x + ((size_t)rc << 8) + col);
        }

        #pragma unroll
        for (int k = 0; k < KP; ++k) {
            const float* cb = comb + ((size_t)lbl[k] << 9) + col;
            const float4 r0 = *reinterpret_cast<const float4*>(cb);
            const float4 r1 = *reinterpret_cast<const float4*>(cb + 256);
            float p0 = xv[k].x*r0.x + xv[k].y*r0.y + xv[k].z*r0.z + xv[k].w*r0.w;
            float p1 = xv[k].x*r1.x + xv[k].y*r1.y + xv[k].z*r1.z + xv[k].w*r1.w;
            const float s0 = wave_sum64(p0);
            const float s1 = wave_sum64(p1);
            const float e0 = (k < nv) ? __expf(s0) : 0.f;
            const float e1 = (k < nv) ? __expf(s1) : 0.f;
            l0 += e0;  l1 += e1;
            o0.x += e0*xv[k].x; o0.y += e0*xv[k].y; o0.z += e0*xv[k].z; o0.w += e0*xv[k].w;
            o1.x += e1*xv[k].x; o1.y += e1*xv[k].y; o1.z += e1*xv[k].z; o1.w += e1*xv[k].w;
        }
    }

    // cross-wave merge in LDS, then write partial record
    __shared__ alignas(16) float s_o[2][NWAVES][HIDDEN];   // 8 KB
    __shared__ float s_l[NWAVES][2];

    *reinterpret_cast<float4*>(&s_o[0][wave][col]) = o0;
    *reinterpret_cast<float4*>(&s_o[1][wave][col]) = o1;
    if (lane == 0) { s_l[wave][0] = l0; s_l[wave][1] = l1; }
    __syncthreads();

    float* pb = part + (size_t)blk * PART_STRIDE;
    {
        const int t = tid;
        const float a0 = s_o[0][0][t] + s_o[0][1][t] + s_o[0][2][t] + s_o[0][3][t];
        const float a1 = s_o[1][0][t] + s_o[1][1][t] + s_o[1][2][t] + s_o[1][3][t];
        pb[t]          = a0;
        pb[HIDDEN + t] = a1;
        if (tid == 0) {
            pb[512] = s_l[0][0] + s_l[1][0] + s_l[2][0] + s_l[3][0];
            pb[513] = s_l[0][1] + s_l[1][1] + s_l[2][1] + s_l[3][1];
        }
    }
}

// ---- Phase 2: merge SPLIT partials per bag, normalize, disc epilogue ----
__global__ __launch_bounds__(BLOCK, 4) void hattn_final_kernel(
    const float* __restrict__ part,
    const float* __restrict__ disc,
    const float* __restrict__ bias,
    float* __restrict__ out)
{
    const int bag = blockIdx.x;
    const int tid = threadIdx.x;

    __shared__ alignas(16) float s_repre[2 * HIDDEN];
    __shared__ float s_inv[2];

    const float* pb = part + (size_t)bag * SPLIT * PART_STRIDE;
    float a0 = 0.f, a1 = 0.f;
    #pragma unroll
    for (int j = 0; j < SPLIT; ++j) {
        a0 += pb[j * PART_STRIDE + tid];
        a1 += pb[j * PART_STRIDE + HIDDEN + tid];
    }
    s_repre[tid]          = a0;
    s_repre[HIDDEN + tid] = a1;
    if (tid == 0) {
        float L0 = 0.f, L1 = 0.f;
        #pragma unroll
        for (int j = 0; j < SPLIT; ++j) {
            L0 += pb[j * PART_STRIDE + 512];
            L1 += pb[j * PART_STRIDE + 513];
        }
        s_inv[0] = (L0 > 0.f) ? 1.f / L0 : 0.f;
        s_inv[1] = (L1 > 0.f) ? 1.f / L1 : 0.f;
    }
    __syncthreads();

    const int c  = tid >> 2;
    const int l4 = tid & 3;
    if (c < NUM_CLASSES) {
        const float4* dr = reinterpret_cast<const float4*>(disc + (size_t)c * (2 * HIDDEN));
        const float4* rp = reinterpret_cast<const float4*>(s_repre);
        float pH0 = 0.f, pH1 = 0.f;
        #pragma unroll
        for (int i = 0; i < 16; ++i) {
            const int idx = l4 + 4 * i;
            const float4 a = rp[idx];
            const float4 d = dr[idx];
            pH0 += a.x*d.x + a.y*d.y + a.z*d.z + a.w*d.w;
        }
        #pragma unroll
        for (int i = 16; i < 32; ++i) {
            const int idx = l4 + 4 * i;
            const float4 a = rp[idx];
            const float4 d = dr[idx];
            pH1 += a.x*d.x + a.y*d.y + a.z*d.z + a.w*d.w;
        }
        float p = pH0 * s_inv[0] + pH1 * s_inv[1];
        p = dpp_add<0xB1>(p);   // quad_perm xor1
        p = dpp_add<0x4E>(p);   // quad_perm xor2
        if (l4 == 0) out[bag * NUM_CLASSES + c] = p + bias[c];
    }
}

// ---- Fallback: monolithic single-pass kernel (no workspace) ----
__global__ __launch_bounds__(BLOCK, 4) void hattn_fused_kernel(
    const float* __restrict__ x,
    const float* __restrict__ rel_emb0,
    const float* __restrict__ rel_emb1,
    const float* __restrict__ disc,
    const float* __restrict__ bias,
    const int* __restrict__ relation_levels,
    const int* __restrict__ label_index,
    const int* __restrict__ scope,
    float* __restrict__ out)
{
    const int bag   = blockIdx.x;
    const int start = __builtin_amdgcn_readfirstlane(scope[bag]);
    const int end   = __builtin_amdgcn_readfirstlane(scope[bag + 1]);

    const int tid  = threadIdx.x;
    const int lane = tid & 63;
    const int wave = tid >> 6;
    const int col  = lane << 2;

    float4 o0 = make_float4(0,0,0,0), o1 = make_float4(0,0,0,0);
    float  l0 = 0.f, l1 = 0.f;

    for (int rb0 = start + wave * KP; rb0 < end; rb0 += NWAVES * KP) {
        const int rb = __builtin_amdgcn_readfirstlane(rb0);
        const int nv = end - rb;
        int lbl[KP]; float4 xv[KP];
        #pragma unroll
        for (int k = 0; k < KP; ++k) {
            const int rc = rb + ((k < nv) ? k : 0);
            lbl[k] = label_index[rc];
            xv[k]  = *reinterpret_cast<const float4*>(x + ((size_t)rc << 8) + col);
        }
        #pragma unroll
        for (int k = 0; k < KP; ++k) {
            const int2 rl = *reinterpret_cast<const int2*>(relation_levels + 2 * lbl[k]);
            const float4 r0 = *reinterpret_cast<const float4*>(rel_emb0 + ((size_t)rl.x << 8) + col);
            const float4 r1 = *reinterpret_cast<const float4*>(rel_emb1 + ((size_t)rl.y << 8) + col);
            float p0 = xv[k].x*r0.x + xv[k].y*r0.y + xv[k].z*r0.z + xv[k].w*r0.w;
            float p1 = xv[k].x*r1.x + xv[k].y*r1.y + xv[k].z*r1.z + xv[k].w*r1.w;
            const float s0 = wave_sum64(p0);
            const float s1 = wave_sum64(p1);
            const float e0 = (k < nv) ? __expf(s0) : 0.f;
            const float e1 = (k < nv) ? __expf(s1) : 0.f;
            l0 += e0;  l1 += e1;
            o0.x += e0*xv[k].x; o0.y += e0*xv[k].y; o0.z += e0*xv[k].z; o0.w += e0*xv[k].w;
            o1.x += e1*xv[k].x; o1.y += e1*xv[k].y; o1.z += e1*xv[k].z; o1.w += e1*xv[k].w;
        }
    }

    __shared__ alignas(16) float s_o[2][NWAVES][HIDDEN];
    __shared__ float s_l[NWAVES][2];
    __shared__ alignas(16) float s_repre[2 * HIDDEN];
    __shared__ float s_inv[2];

    *reinterpret_cast<float4*>(&s_o[0][wave][col]) = o0;
    *reinterpret_cast<float4*>(&s_o[1][wave][col]) = o1;
    if (lane == 0) { s_l[wave][0] = l0; s_l[wave][1] = l1; }
    __syncthreads();

    {
        const int t = tid;
        s_repre[t]          = s_o[0][0][t] + s_o[0][1][t] + s_o[0][2][t] + s_o[0][3][t];
        s_repre[HIDDEN + t] = s_o[1][0][t] + s_o[1][1][t] + s_o[1][2][t] + s_o[1][3][t];
        if (tid == 0) {
            const float L0 = s_l[0][0] + s_l[1][0] + s_l[2][0] + s_l[3][0];
            const float L1 = s_l[0][1] + s_l[1][1] + s_l[2][1] + s_l[3][1];
            s_inv[0] = (L0 > 0.f) ? 1.f / L0 : 0.f;
            s_inv[1] = (L1 > 0.f) ? 1.f / L1 : 0.f;
        }
    }
    __syncthreads();

    const int c  = tid >> 2;
    const int l4 = tid & 3;
    if (c < NUM_CLASSES) {
        const float4* dr = reinterpret_cast<const float4*>(disc + (size_t)c * (2 * HIDDEN));
        const float4* rp = reinterpret_cast<const float4*>(s_repre);
        float pH0 = 0.f, pH1 = 0.f;
        #pragma unroll
        for (int i = 0; i < 16; ++i) {
            const int idx = l4 + 4 * i;
            const float4 a = rp[idx]; const float4 d = dr[idx];
            pH0 += a.x*d.x + a.y*d.y + a.z*d.z + a.w*d.w;
        }
        #pragma unroll
        for (int i = 16; i < 32; ++i) {
            const int idx = l4 + 4 * i;
            const float4 a = rp[idx]; const float4 d = dr[idx];
            pH1 += a.x*d.x + a.y*d.y + a.z*d.z + a.w*d.w;
        }
        float p = pH0 * s_inv[0] + pH1 * s_inv[1];
        p = dpp_add<0xB1>(p);
        p = dpp_add<0x4E>(p);
        if (l4 == 0) out[bag * NUM_CLASSES + c] = p + bias[c];
    }
}

extern "C" void kernel_launch(void* const* d_in, const int* in_sizes, int n_in,
                              void* d_out, int out_size, void* d_ws, size_t ws_size,
                              hipStream_t stream) {
    const float* x               = (const float*)d_in[0];
    const float* rel_emb0        = (const float*)d_in[1];
    const float* rel_emb1        = (const float*)d_in[2];
    const float* disc            = (const float*)d_in[3];
    const float* bias            = (const float*)d_in[4];
    const int*   relation_levels = (const int*)d_in[5];
    const int*   label_index     = (const int*)d_in[6];
    const int*   scope           = (const int*)d_in[7];
    float*       out             = (float*)d_out;

    const int n_bags = in_sizes[7] - 1;   // 4096
    const size_t part_bytes = (size_t)n_bags * SPLIT * PART_STRIDE * sizeof(float);

    if (d_ws != nullptr && ws_size >= COMB_BYTES + part_bytes) {
        float* comb = (float*)d_ws;
        float* part = comb + COMB_FLOATS;
        build_comb_kernel<<<NUM_CLASSES, HIDDEN, 0, stream>>>(
            rel_emb0, rel_emb1, relation_levels, comb);
        hattn_partial_kernel<<<n_bags * SPLIT, BLOCK, 0, stream>>>(
            x, comb, label_index, scope, part);
        hattn_final_kernel<<<n_bags, BLOCK, 0, stream>>>(
            part, disc, bias, out);
    } else {
        hattn_fused_kernel<<<n_bags, BLOCK, 0, stream>>>(
            x, rel_emb0, rel_emb1, disc, bias,
            relation_levels, label_index, scope, out);
    }
}

// Round 10
// 422.156 us; speedup vs baseline: 1.0048x; 1.0048x over previous
//
#include <hip/hip_runtime.h>
#include <math.h>

#define HIDDEN 256
#define NUM_CLASSES 53
#define NWAVES 4
#define BLOCK (NWAVES * 64)
#define KP 4                       // rows per group in stream kernel
#define RPW 64                     // rows per wave in stream kernel
#define COMB_FLOATS (NUM_CLASSES * 2 * HIDDEN)

// v += dpp_mov(v, CTRL); bound_ctrl: out-of-range sources read 0
template <int CTRL>
__device__ __forceinline__ float dpp_add(float v) {
    int t = __builtin_amdgcn_update_dpp(0, __float_as_int(v), CTRL, 0xf, 0xf, true);
    return v + __int_as_float(t);
}

// Full 64-lane sum -> wave-uniform (readlane 63)
__device__ __forceinline__ float wave_sum64(float v) {
    v = dpp_add<0x111>(v);   // row_shr:1
    v = dpp_add<0x112>(v);   // row_shr:2
    v = dpp_add<0x114>(v);   // row_shr:4
    v = dpp_add<0x118>(v);   // row_shr:8
    v = dpp_add<0x142>(v);   // row_bcast:15
    v = dpp_add<0x143>(v);   // row_bcast:31 -> lane63 = total
    return __int_as_float(__builtin_amdgcn_readlane(__float_as_int(v), 63));
}

// comb[c][0:256] = rel_emb0[rl[c].x], comb[c][256:512] = rel_emb1[rl[c].y]
__global__ void build_comb_kernel(const float* __restrict__ rel_emb0,
                                  const float* __restrict__ rel_emb1,
                                  const int* __restrict__ relation_levels,
                                  float* __restrict__ comb) {
    const int c = blockIdx.x;
    const int t = threadIdx.x;
    const int2 rl = *reinterpret_cast<const int2*>(relation_levels + 2 * c);
    comb[c * 512 + t]       = rel_emb0[rl.x * HIDDEN + t];
    comb[c * 512 + 256 + t] = rel_emb1[rl.y * HIDDEN + t];
}

// seg[r] = bag containing row r
__global__ void build_seg_kernel(const int* __restrict__ scope,
                                 int* __restrict__ seg) {
    const int b = blockIdx.x;
    const int s = scope[b], e = scope[b + 1];
    for (int r = s + threadIdx.x; r < e; r += blockDim.x) seg[r] = b;
}

__global__ void zero_acc_kernel(float* __restrict__ acc,
                                float* __restrict__ accL, int n_bags) {
    const int stride = gridDim.x * blockDim.x;
    const int total = n_bags * 512;
    for (int i = blockIdx.x * blockDim.x + threadIdx.x; i < total; i += stride)
        acc[i] = 0.f;
    for (int j = blockIdx.x * blockDim.x + threadIdx.x; j < n_bags * 2; j += stride)
        accL[j] = 0.f;
}

// ---- stream kernel: contiguous rows, register accumulation, atomic flush per bag ----
__global__ __launch_bounds__(BLOCK, 4) void hattn_stream_kernel(
    const float* __restrict__ x,
    const float* __restrict__ comb,
    const int* __restrict__ label_index,
    const int* __restrict__ seg,
    float* __restrict__ acc,
    float* __restrict__ accL,
    int n)
{
    const int tid  = threadIdx.x;
    const int lane = tid & 63;
    const int wave = tid >> 6;
    const int col  = lane << 2;                 // 4 hidden cols per lane
    const int wg   = blockIdx.x * NWAVES + wave;
    const int r0   = wg * RPW;
    if (r0 >= n) return;
    const int rend = (r0 + RPW < n) ? (r0 + RPW) : n;

    float4 o0 = make_float4(0,0,0,0), o1 = make_float4(0,0,0,0);
    float  l0 = 0.f, l1 = 0.f;
    int cur = __builtin_amdgcn_readfirstlane(seg[r0]);

    auto flush = [&](int b) {
        float* a = acc + ((size_t)b << 9) + col;
        unsafeAtomicAdd(a + 0,   o0.x); unsafeAtomicAdd(a + 1,   o0.y);
        unsafeAtomicAdd(a + 2,   o0.z); unsafeAtomicAdd(a + 3,   o0.w);
        unsafeAtomicAdd(a + 256, o1.x); unsafeAtomicAdd(a + 257, o1.y);
        unsafeAtomicAdd(a + 258, o1.z); unsafeAtomicAdd(a + 259, o1.w);
        if (lane == 0) {
            unsafeAtomicAdd(accL + 2 * b,     l0);
            unsafeAtomicAdd(accL + 2 * b + 1, l1);
        }
        o0 = make_float4(0,0,0,0); o1 = make_float4(0,0,0,0);
        l0 = 0.f; l1 = 0.f;
    };

    for (int g = r0; g < rend; g += KP) {
        const int m = rend - g;                 // rows left (>=1)
        int sg[KP], lb[KP];
        float4 xv[KP];
        #pragma unroll
        for (int k = 0; k < KP; ++k) {
            const int r = g + ((k < m) ? k : 0);
            sg[k] = seg[r];                     // uniform -> s_load
            lb[k] = label_index[r];             // uniform -> s_load
            xv[k] = *reinterpret_cast<const float4*>(x + ((size_t)r << 8) + col);
        }
        float4 c0[KP], c1[KP];
        #pragma unroll
        for (int k = 0; k < KP; ++k) {
            const float* cb = comb + ((size_t)lb[k] << 9) + col;
            c0[k] = *reinterpret_cast<const float4*>(cb);
            c1[k] = *reinterpret_cast<const float4*>(cb + 256);
        }
        #pragma unroll
        for (int k = 0; k < KP; ++k) {
            if (k < m) {
                float p0 = xv[k].x*c0[k].x + xv[k].y*c0[k].y + xv[k].z*c0[k].z + xv[k].w*c0[k].w;
                float p1 = xv[k].x*c1[k].x + xv[k].y*c1[k].y + xv[k].z*c1[k].z + xv[k].w*c1[k].w;
                const float s0 = wave_sum64(p0);
                const float s1 = wave_sum64(p1);
                const float e0 = __expf(s0);
                const float e1 = __expf(s1);
                if (sg[k] != cur) { flush(cur); cur = sg[k]; }   // wave-uniform branch
                l0 += e0;  l1 += e1;
                o0.x += e0*xv[k].x; o0.y += e0*xv[k].y; o0.z += e0*xv[k].z; o0.w += e0*xv[k].w;
                o1.x += e1*xv[k].x; o1.y += e1*xv[k].y; o1.z += e1*xv[k].z; o1.w += e1*xv[k].w;
            }
        }
    }
    flush(cur);
}

// ---- final: normalize per bag + disc epilogue ----
__global__ __launch_bounds__(BLOCK, 4) void hattn_final_kernel(
    const float* __restrict__ acc,
    const float* __restrict__ accL,
    const float* __restrict__ disc,
    const float* __restrict__ bias,
    float* __restrict__ out)
{
    const int bag = blockIdx.x;
    const int tid = threadIdx.x;

    __shared__ alignas(16) float s_repre[2 * HIDDEN];
    __shared__ float s_inv[2];

    s_repre[tid]          = acc[(size_t)bag * 512 + tid];
    s_repre[HIDDEN + tid] = acc[(size_t)bag * 512 + HIDDEN + tid];
    if (tid == 0) {
        const float L0 = accL[2 * bag];
        const float L1 = accL[2 * bag + 1];
        s_inv[0] = (L0 > 0.f) ? 1.f / L0 : 0.f;
        s_inv[1] = (L1 > 0.f) ? 1.f / L1 : 0.f;
    }
    __syncthreads();

    const int c  = tid >> 2;
    const int l4 = tid & 3;
    if (c < NUM_CLASSES) {
        const float4* dr = reinterpret_cast<const float4*>(disc + (size_t)c * (2 * HIDDEN));
        const float4* rp = reinterpret_cast<const float4*>(s_repre);
        float pH0 = 0.f, pH1 = 0.f;
        #pragma unroll
        for (int i = 0; i < 16; ++i) {
            const int idx = l4 + 4 * i;
            const float4 a = rp[idx]; const float4 d = dr[idx];
            pH0 += a.x*d.x + a.y*d.y + a.z*d.z + a.w*d.w;
        }
        #pragma unroll
        for (int i = 16; i < 32; ++i) {
            const int idx = l4 + 4 * i;
            const float4 a = rp[idx]; const float4 d = dr[idx];
            pH1 += a.x*d.x + a.y*d.y + a.z*d.z + a.w*d.w;
        }
        float p = pH0 * s_inv[0] + pH1 * s_inv[1];
        p = dpp_add<0xB1>(p);   // quad_perm xor1
        p = dpp_add<0x4E>(p);   // quad_perm xor2
        if (l4 == 0) out[bag * NUM_CLASSES + c] = p + bias[c];
    }
}

// ---- Fallback: monolithic single-pass kernel (no workspace) ----
__global__ __launch_bounds__(BLOCK, 4) void hattn_fused_kernel(
    const float* __restrict__ x,
    const float* __restrict__ rel_emb0,
    const float* __restrict__ rel_emb1,
    const float* __restrict__ disc,
    const float* __restrict__ bias,
    const int* __restrict__ relation_levels,
    const int* __restrict__ label_index,
    const int* __restrict__ scope,
    float* __restrict__ out)
{
    const int bag   = blockIdx.x;
    const int start = __builtin_amdgcn_readfirstlane(scope[bag]);
    const int end   = __builtin_amdgcn_readfirstlane(scope[bag + 1]);

    const int tid  = threadIdx.x;
    const int lane = tid & 63;
    const int wave = tid >> 6;
    const int col  = lane << 2;

    float4 o0 = make_float4(0,0,0,0), o1 = make_float4(0,0,0,0);
    float  l0 = 0.f, l1 = 0.f;

    for (int rb0 = start + wave * KP; rb0 < end; rb0 += NWAVES * KP) {
        const int rb = __builtin_amdgcn_readfirstlane(rb0);
        const int nv = end - rb;
        int lbl[KP]; float4 xv[KP];
        #pragma unroll
        for (int k = 0; k < KP; ++k) {
            const int rc = rb + ((k < nv) ? k : 0);
            lbl[k] = label_index[rc];
            xv[k]  = *reinterpret_cast<const float4*>(x + ((size_t)rc << 8) + col);
        }
        #pragma unroll
        for (int k = 0; k < KP; ++k) {
            const int2 rl = *reinterpret_cast<const int2*>(relation_levels + 2 * lbl[k]);
            const float4 r0 = *reinterpret_cast<const float4*>(rel_emb0 + ((size_t)rl.x << 8) + col);
            const float4 r1 = *reinterpret_cast<const float4*>(rel_emb1 + ((size_t)rl.y << 8) + col);
            float p0 = xv[k].x*r0.x + xv[k].y*r0.y + xv[k].z*r0.z + xv[k].w*r0.w;
            float p1 = xv[k].x*r1.x + xv[k].y*r1.y + xv[k].z*r1.z + xv[k].w*r1.w;
            const float s0 = wave_sum64(p0);
            const float s1 = wave_sum64(p1);
            const float e0 = (k < nv) ? __expf(s0) : 0.f;
            const float e1 = (k < nv) ? __expf(s1) : 0.f;
            l0 += e0;  l1 += e1;
            o0.x += e0*xv[k].x; o0.y += e0*xv[k].y; o0.z += e0*xv[k].z; o0.w += e0*xv[k].w;
            o1.x += e1*xv[k].x; o1.y += e1*xv[k].y; o1.z += e1*xv[k].z; o1.w += e1*xv[k].w;
        }
    }

    __shared__ alignas(16) float s_o[2][NWAVES][HIDDEN];
    __shared__ float s_l[NWAVES][2];
    __shared__ alignas(16) float s_repre[2 * HIDDEN];
    __shared__ float s_inv[2];

    *reinterpret_cast<float4*>(&s_o[0][wave][col]) = o0;
    *reinterpret_cast<float4*>(&s_o[1][wave][col]) = o1;
    if (lane == 0) { s_l[wave][0] = l0; s_l[wave][1] = l1; }
    __syncthreads();

    {
        const int t = tid;
        s_repre[t]          = s_o[0][0][t] + s_o[0][1][t] + s_o[0][2][t] + s_o[0][3][t];
        s_repre[HIDDEN + t] = s_o[1][0][t] + s_o[1][1][t] + s_o[1][2][t] + s_o[1][3][t];
        if (tid == 0) {
            const float L0 = s_l[0][0] + s_l[1][0] + s_l[2][0] + s_l[3][0];
            const float L1 = s_l[0][1] + s_l[1][1] + s_l[2][1] + s_l[3][1];
            s_inv[0] = (L0 > 0.f) ? 1.f / L0 : 0.f;
            s_inv[1] = (L1 > 0.f) ? 1.f / L1 : 0.f;
        }
    }
    __syncthreads();

    const int c  = tid >> 2;
    const int l4 = tid & 3;
    if (c < NUM_CLASSES) {
        const float4* dr = reinterpret_cast<const float4*>(disc + (size_t)c * (2 * HIDDEN));
        const float4* rp = reinterpret_cast<const float4*>(s_repre);
        float pH0 = 0.f, pH1 = 0.f;
        #pragma unroll
        for (int i = 0; i < 16; ++i) {
            const int idx = l4 + 4 * i;
            const float4 a = rp[idx]; const float4 d = dr[idx];
            pH0 += a.x*d.x + a.y*d.y + a.z*d.z + a.w*d.w;
        }
        #pragma unroll
        for (int i = 16; i < 32; ++i) {
            const int idx = l4 + 4 * i;
            const float4 a = rp[idx]; const float4 d = dr[idx];
            pH1 += a.x*d.x + a.y*d.y + a.z*d.z + a.w*d.w;
        }
        float p = pH0 * s_inv[0] + pH1 * s_inv[1];
        p = dpp_add<0xB1>(p);
        p = dpp_add<0x4E>(p);
        if (l4 == 0) out[bag * NUM_CLASSES + c] = p + bias[c];
    }
}

extern "C" void kernel_launch(void* const* d_in, const int* in_sizes, int n_in,
                              void* d_out, int out_size, void* d_ws, size_t ws_size,
                              hipStream_t stream) {
    const float* x               = (const float*)d_in[0];
    const float* rel_emb0        = (const float*)d_in[1];
    const float* rel_emb1        = (const float*)d_in[2];
    const float* disc            = (const float*)d_in[3];
    const float* bias            = (const float*)d_in[4];
    const int*   relation_levels = (const int*)d_in[5];
    const int*   label_index     = (const int*)d_in[6];
    const int*   scope           = (const int*)d_in[7];
    float*       out             = (float*)d_out;

    const int n_bags = in_sizes[7] - 1;        // 4096
    const int n      = in_sizes[6];            // 262144 sentences

    // workspace layout: comb | acc | accL | seg
    const size_t comb_f = COMB_FLOATS;
    const size_t acc_f  = (size_t)n_bags * 512;
    const size_t accL_f = (size_t)n_bags * 2;
    const size_t need   = (comb_f + acc_f + accL_f) * 4 + (size_t)n * 4;

    if (d_ws != nullptr && ws_size >= need) {
        float* comb = (float*)d_ws;
        float* acc  = comb + comb_f;
        float* accL = acc + acc_f;
        int*   seg  = (int*)(accL + accL_f);

        build_comb_kernel<<<NUM_CLASSES, HIDDEN, 0, stream>>>(
            rel_emb0, rel_emb1, relation_levels, comb);
        build_seg_kernel<<<n_bags, 256, 0, stream>>>(scope, seg);
        zero_acc_kernel<<<512, 256, 0, stream>>>(acc, accL, n_bags);

        const int n_wg = (n + RPW * NWAVES - 1) / (RPW * NWAVES);   // 1024
        hattn_stream_kernel<<<n_wg, BLOCK, 0, stream>>>(
            x, comb, label_index, seg, acc, accL, n);
        hattn_final_kernel<<<n_bags, BLOCK, 0, stream>>>(
            acc, accL, disc, bias, out);
    } else {
        hattn_fused_kernel<<<n_bags, BLOCK, 0, stream>>>(
            x, rel_emb0, rel_emb1, disc, bias,
            relation_levels, label_index, scope, out);
    }
}